// Round 10
// baseline (261.824 us; speedup 1.0000x reference)
//
#include <hip/hip_runtime.h>
#include <float.h>
#include <limits.h>
#include <math.h>

// ClusterLayer: B=131072 rows, K=1024 clusters, D=128.
// out (float32): [0] inertia/B, [1] xe/K, [2..2+B) cl as float.
//
// R10: dist = R9's 1-pass RNE-fp16 MFMA (lean tracker, counted-vmcnt dbuf).
// refine rewritten: coalesced lane split (kpart=lane&7 contiguous dims),
// 4 rows per wave per W pass (W traffic /4, 4x ILP), wave-parallel f64 pair.
//
// ws layout (bytes):
//   0      : double inertia_acc
//   8      : int    flag_cnt
//   16     : float  w2[1024]
//   4608   : short  wh[131072]     (256 KB, fp16-RNE W, tile fragment order)
//   266752 : int    flag_rows[32768]  -> end 397824

#define TAU 4e-3f

using f16x8  = __attribute__((ext_vector_type(8))) _Float16;
using bf16x8 = __attribute__((ext_vector_type(8))) short;
using f32x4  = __attribute__((ext_vector_type(4))) float;
using s16x4  = __attribute__((ext_vector_type(4))) short;

static __device__ __forceinline__ short f2bf_trunc(float f) {
    return (short)(__float_as_uint(f) >> 16);
}
static __device__ __forceinline__ float bf2f(short h) {
    return __uint_as_float(((unsigned int)(unsigned short)h) << 16);
}
static __device__ __forceinline__ bool lexlt(float v1, int i1, float v2, int i2) {
    return v1 < v2 || (v1 == v2 && i1 < i2);
}
static __device__ __forceinline__ void gload_lds16(const void* g, void* l) {
    __builtin_amdgcn_global_load_lds(
        (const __attribute__((address_space(1))) unsigned int*)g,
        (__attribute__((address_space(3))) unsigned int*)l, 16, 0, 0);
}
#define FENCE() do { asm volatile("" ::: "memory"); __builtin_amdgcn_sched_barrier(0); } while (0)

// W prep: w2 per cluster (f32-exact) + fp16-RNE image in 64-col-tile fragment
// order: shorts: tile*8192 + (c>>4)*2048 + (d>>5)*512 + ((d>>3)&3)*128
//                + (c&15)*8 + (d&7);   tile=k>>6, c=k&63
__global__ void wprep_kernel(const float* __restrict__ W, float* __restrict__ w2,
                             short* __restrict__ wh, int write_wh)
{
    const int k = blockIdx.x;
    const int d = threadIdx.x;     // 0..127
    float v = W[(size_t)k * 128 + d];
    float sq = v * v;
    for (int off = 1; off < 64; off <<= 1) sq += __shfl_xor(sq, off, 64);
    __shared__ float p[2];
    if ((d & 63) == 0) p[d >> 6] = sq;
    __syncthreads();
    if (d == 0) w2[k] = p[0] + p[1];
    if (write_wh) {
        _Float16 h = (_Float16)v;                       // RNE
        const int tile = k >> 6, c = k & 63;
        size_t base = (size_t)tile * 8192 + (size_t)(c >> 4) * 2048 + (size_t)(d >> 5) * 512
                    + (size_t)((d >> 3) & 3) * 128 + (size_t)(c & 15) * 8 + (size_t)(d & 7);
        wh[base] = *reinterpret_cast<short*>(&h);
    }
}

// LDS (bytes): lB0 0..32768 | lB1 32768..65536 | lw2 65536..69632 |
//              lx2 69632..70144 | mscr 70144..72192 (128 x 4 ints) |
//              dred 72192..72320
__global__ __launch_bounds__(512, 4)
void dist_argmin_1p(const float* __restrict__ X, const short* __restrict__ wh,
                    const float* __restrict__ w2g, float* __restrict__ cl_out,
                    double* __restrict__ inertia_acc,
                    int* __restrict__ flag_cnt, int* __restrict__ flag_rows,
                    int flag_cap)
{
    __shared__ __align__(16) char smem[72320];
    char*   lB0  = smem;
    char*   lB1  = smem + 32768;
    float*  lw2  = (float*)(smem + 65536);
    float*  lx2  = (float*)(smem + 69632);
    int*    mscr = (int*)(smem + 70144);
    double* dred = (double*)(smem + 72192);

    const int tid    = threadIdx.x;
    const int lane   = tid & 63;
    const int laneLo = lane & 15;
    const int laneHi = lane >> 4;
    const int wid    = tid >> 6;
    const int rowg   = wid >> 1;
    const int colg   = wid & 1;
    const int rowbase = blockIdx.x * 128;

    // w2 -> LDS (K-loop must have zero global loads so vmcnt counting holds)
    lw2[tid]       = w2g[tid];
    lw2[tid + 512] = w2g[tid + 512];

    // ---- A (fp16 RNE) straight from global into registers + ||x||^2 ----
    f16x8 ah[2][4];
    #pragma unroll
    for (int m = 0; m < 2; ++m) {
        const float* xp = X + (size_t)(rowbase + rowg * 32 + m * 16 + laneLo) * 128 + laneHi * 8;
        float s = 0.f;
        #pragma unroll
        for (int k0b = 0; k0b < 4; ++k0b) {
            float4 v0 = *reinterpret_cast<const float4*>(xp + k0b * 32);
            float4 v1 = *reinterpret_cast<const float4*>(xp + k0b * 32 + 4);
            float fv[8] = {v0.x, v0.y, v0.z, v0.w, v1.x, v1.y, v1.z, v1.w};
            f16x8 hv;
            #pragma unroll
            for (int u = 0; u < 8; ++u) {
                s = fmaf(fv[u], fv[u], s);
                hv[u] = (_Float16)fv[u];               // RNE
            }
            ah[m][k0b] = hv;
        }
        s += __shfl_xor(s, 16, 64);     // combine 4 laneHi dim-slices
        s += __shfl_xor(s, 32, 64);
        if (colg == 0 && laneHi == 0) lx2[rowg * 32 + m * 16 + laneLo] = s;
    }

    // ---- issue phase 0 DMA -> lB0 (32 KB = 128 clusters; 4 x 16B/thread) ----
    #pragma unroll
    for (int q = 0; q < 4; ++q)
        gload_lds16((const char*)wh + wid * 4096 + q * 1024 + lane * 16,
                    lB0 + wid * 4096 + q * 1024);

    // drain my lw2/lx2 ds_writes before the first in-loop barrier
    asm volatile("s_waitcnt lgkmcnt(0)" ::: "memory");
    __builtin_amdgcn_sched_barrier(0);

    float t1v[2][4], t2v[2][4];
    int   t1i[2][4];
    #pragma unroll
    for (int m = 0; m < 2; ++m)
        #pragma unroll
        for (int r = 0; r < 4; ++r) {
            t1v[m][r] = FLT_MAX; t2v[m][r] = FLT_MAX; t1i[m][r] = INT_MAX;
        }

    // one 16KB tile = 64 clusters; ti = global tile index (0..15)
    auto compute = [&](int ti, const char* tileBase) {
        const char* pBb = tileBase + colg * 8192 + lane * 16;
        float w2v[2];
        #pragma unroll
        for (int nt = 0; nt < 2; ++nt)
            w2v[nt] = lw2[ti * 64 + colg * 32 + nt * 16 + laneLo];

        __builtin_amdgcn_s_setprio(1);
        #pragma unroll
        for (int nt = 0; nt < 2; ++nt) {
            f32x4 a0 = (f32x4){0.f, 0.f, 0.f, 0.f};
            f32x4 a1 = (f32x4){0.f, 0.f, 0.f, 0.f};
            #pragma unroll
            for (int k0b = 0; k0b < 4; ++k0b) {
                f16x8 bh = *reinterpret_cast<const f16x8*>(pBb + nt * 4096 + k0b * 1024);
                a0 = __builtin_amdgcn_mfma_f32_16x16x32_f16(ah[0][k0b], bh, a0, 0, 0, 0);
                a1 = __builtin_amdgcn_mfma_f32_16x16x32_f16(ah[1][k0b], bh, a1, 0, 0, 0);
            }
            // dist = w2 - 2*dot_f16; branch-free top-2 values + top-1 index.
            const int col = ti * 64 + colg * 32 + nt * 16 + laneLo;
            #pragma unroll
            for (int r = 0; r < 4; ++r) {
                float dv0 = fmaf(-2.f, a0[r], w2v[nt]);
                t2v[0][r] = fminf(t2v[0][r], fmaxf(t1v[0][r], dv0));
                t1i[0][r] = (dv0 < t1v[0][r]) ? col : t1i[0][r];
                t1v[0][r] = fminf(t1v[0][r], dv0);
                float dv1 = fmaf(-2.f, a1[r], w2v[nt]);
                t2v[1][r] = fminf(t2v[1][r], fmaxf(t1v[1][r], dv1));
                t1i[1][r] = (dv1 < t1v[1][r]) ? col : t1i[1][r];
                t1v[1][r] = fminf(t1v[1][r], dv1);
            }
        }
        __builtin_amdgcn_s_setprio(0);
    };

    const char* cur = lB0;
    char*       nxt = lB1;
    #pragma unroll 1
    for (int p = 0; p < 8; ++p) {
        if (p < 7) {
            const char* src = (const char*)wh + (size_t)(p + 1) * 32768;
            #pragma unroll
            for (int q = 0; q < 4; ++q)
                gload_lds16(src + wid * 4096 + q * 1024 + lane * 16,
                            nxt + wid * 4096 + q * 1024);
            asm volatile("s_waitcnt vmcnt(4)" ::: "memory");  // phase p landed; p+1 in flight
        } else {
            asm volatile("s_waitcnt vmcnt(0)" ::: "memory");
        }
        __builtin_amdgcn_sched_barrier(0);
        __builtin_amdgcn_s_barrier();                         // everyone's phase p landed
        FENCE();
        compute(2 * p,     cur);
        compute(2 * p + 1, cur + 16384);
        if (p < 7) {
            asm volatile("s_waitcnt lgkmcnt(0)" ::: "memory");
            __builtin_amdgcn_sched_barrier(0);
            __builtin_amdgcn_s_barrier();                     // all waves done reading cur
            FENCE();
            char* tmp = nxt; nxt = (char*)cur; cur = tmp;
        }
    }

    // ---- reduce top-2 across the 16 col-lanes (laneLo) of each row ----
    #pragma unroll
    for (int off = 1; off < 16; off <<= 1) {
        #pragma unroll
        for (int m = 0; m < 2; ++m)
            #pragma unroll
            for (int r = 0; r < 4; ++r) {
                float ov1 = __shfl_xor(t1v[m][r], off, 64);
                int   oi1 = __shfl_xor(t1i[m][r], off, 64);
                float ov2 = __shfl_xor(t2v[m][r], off, 64);
                float nt2 = fminf(fminf(t2v[m][r], ov2), fmaxf(t1v[m][r], ov1));
                if (lexlt(ov1, oi1, t1v[m][r], t1i[m][r])) { t1v[m][r] = ov1; t1i[m][r] = oi1; }
                t2v[m][r] = nt2;
            }
    }

    // ---- merge col-halves via LDS ----
    __syncthreads();
    if (colg == 1 && laneLo == 0) {
        #pragma unroll
        for (int m = 0; m < 2; ++m)
            #pragma unroll
            for (int r = 0; r < 4; ++r) {
                const int row = rowg * 32 + m * 16 + laneHi * 4 + r;
                mscr[row * 4 + 0] = __float_as_int(t1v[m][r]);
                mscr[row * 4 + 1] = t1i[m][r];
                mscr[row * 4 + 2] = __float_as_int(t2v[m][r]);
            }
    }
    __syncthreads();
    double local = 0.0;
    if (colg == 0 && laneLo == 0) {
        #pragma unroll
        for (int m = 0; m < 2; ++m)
            #pragma unroll
            for (int r = 0; r < 4; ++r) {
                const int row = rowg * 32 + m * 16 + laneHi * 4 + r;
                float ov1 = __int_as_float(mscr[row * 4 + 0]);
                int   oi1 = mscr[row * 4 + 1];
                float ov2 = __int_as_float(mscr[row * 4 + 2]);
                float b1v = t1v[m][r], b2v;
                int   b1i = t1i[m][r];
                b2v = fminf(fminf(t2v[m][r], ov2), fmaxf(b1v, ov1));
                if (lexlt(ov1, oi1, b1v, b1i)) { b1v = ov1; b1i = oi1; }
                const int grow = rowbase + row;
                if (b2v - b1v < TAU) {                 // near-tie: exact rescan
                    int slot = atomicAdd(flag_cnt, 1);
                    if (slot < flag_cap) {
                        flag_rows[slot] = grow;
                    } else {
                        cl_out[grow] = (float)b1i;
                        local += (double)(b1v + lx2[row]);
                    }
                } else {
                    cl_out[grow] = (float)b1i;
                    local += (double)(b1v + lx2[row]);
                }
            }
        dred[rowg * 4 + laneHi] = local;
    }
    __syncthreads();
    if (tid == 0) {
        double tt = 0.0;
        for (int i = 0; i < 16; ++i) tt += dred[i];
        atomicAdd(inertia_acc, tt);
    }
}

// refine: one WAVE per group of 4 flagged rows. lane=(cgrp,kpart):
// kpart=lane&7 owns dims kpart*16..+16 (contiguous -> coalesced W/X reads),
// cgrp=lane>>3 owns clusters cgrp*128..+128. W read once per 4 rows.
// f32 rescan -> top-2 (lexicographic) -> 64-lane-parallel exact f64 pair.
__global__ __launch_bounds__(256)
void refine_kernel(const float* __restrict__ X, const float* __restrict__ W,
                   const float* __restrict__ w2,
                   const int* __restrict__ flag_cnt,
                   const int* __restrict__ flag_rows, int flag_cap,
                   float* __restrict__ cl_out, double* __restrict__ inertia_acc)
{
    int n = *flag_cnt;
    if (n > flag_cap) n = flag_cap;
    if (n <= 0) return;
    const int lane  = threadIdx.x & 63;
    const int wv    = threadIdx.x >> 6;
    const int kpart = lane & 7;       // contiguous dim segment -> coalesced
    const int cgrp  = lane >> 3;      // 0..7

    const int ngroups = (n + 3) >> 2;
    for (int g = blockIdx.x * 4 + wv; g < ngroups; g += gridDim.x * 4) {
        int  rows[4];
        bool valid[4];
        #pragma unroll
        for (int r = 0; r < 4; ++r) {
            const int f = g * 4 + r;
            valid[r] = (f < n);
            rows[r]  = flag_rows[valid[r] ? f : (n - 1)];
        }
        // 4 X-row segments (16 floats each) in registers
        float4 xa[4][4];
        #pragma unroll
        for (int r = 0; r < 4; ++r) {
            const float* xk = X + (size_t)rows[r] * 128 + kpart * 16;
            xa[r][0] = *reinterpret_cast<const float4*>(xk);
            xa[r][1] = *reinterpret_cast<const float4*>(xk + 4);
            xa[r][2] = *reinterpret_cast<const float4*>(xk + 8);
            xa[r][3] = *reinterpret_cast<const float4*>(xk + 12);
        }

        float v1[4], v2[4];
        int   i1[4], i2[4];
        #pragma unroll
        for (int r = 0; r < 4; ++r) { v1[r] = FLT_MAX; v2[r] = FLT_MAX; i1[r] = INT_MAX; i2[r] = INT_MAX; }

        #pragma unroll 2
        for (int q = 0; q < 128; ++q) {
            const int c = cgrp * 128 + q;
            const float* wr = W + (size_t)c * 128 + kpart * 16;
            float4 w0 = *reinterpret_cast<const float4*>(wr);
            float4 w1 = *reinterpret_cast<const float4*>(wr + 4);
            float4 w2f = *reinterpret_cast<const float4*>(wr + 8);
            float4 w3 = *reinterpret_cast<const float4*>(wr + 12);
            const float w2c = w2[c];
            #pragma unroll
            for (int r = 0; r < 4; ++r) {
                float p0 = fmaf(xa[r][0].w, w0.w, fmaf(xa[r][0].z, w0.z, fmaf(xa[r][0].y, w0.y, xa[r][0].x * w0.x)));
                float p1 = fmaf(xa[r][1].w, w1.w, fmaf(xa[r][1].z, w1.z, fmaf(xa[r][1].y, w1.y, xa[r][1].x * w1.x)));
                float p2 = fmaf(xa[r][2].w, w2f.w, fmaf(xa[r][2].z, w2f.z, fmaf(xa[r][2].y, w2f.y, xa[r][2].x * w2f.x)));
                float p3 = fmaf(xa[r][3].w, w3.w, fmaf(xa[r][3].z, w3.z, fmaf(xa[r][3].y, w3.y, xa[r][3].x * w3.x)));
                float p = (p0 + p1) + (p2 + p3);
                p += __shfl_xor(p, 1, 64);      // reduce over kpart (lane&7)
                p += __shfl_xor(p, 2, 64);
                p += __shfl_xor(p, 4, 64);
                float dv = fmaf(-2.f, p, w2c);
                if (dv < v1[r]) { v2[r] = v1[r]; i2[r] = i1[r]; v1[r] = dv; i1[r] = c; }  // c ascending
                else if (dv < v2[r]) { v2[r] = dv; i2[r] = c; }
            }
        }
        // merge top-2 across the 8 cgrps (xor 8,16,32)
        #pragma unroll
        for (int off = 8; off < 64; off <<= 1) {
            #pragma unroll
            for (int r = 0; r < 4; ++r) {
                float ov1 = __shfl_xor(v1[r], off, 64);
                int   oi1 = __shfl_xor(i1[r], off, 64);
                float ov2 = __shfl_xor(v2[r], off, 64);
                int   oi2 = __shfl_xor(i2[r], off, 64);
                if (lexlt(ov1, oi1, v1[r], i1[r])) {
                    float nv2; int ni2;
                    if (lexlt(v1[r], i1[r], ov2, oi2)) { nv2 = v1[r]; ni2 = i1[r]; }
                    else                               { nv2 = ov2;   ni2 = oi2; }
                    v1[r] = ov1; i1[r] = oi1; v2[r] = nv2; i2[r] = ni2;
                } else if (lexlt(ov1, oi1, v2[r], i2[r])) {
                    v2[r] = ov1; i2[r] = oi1;
                }
            }
        }
        // exact f64 pair decision per row, parallel over 64 lanes (2 dims each)
        #pragma unroll
        for (int r = 0; r < 4; ++r) {
            if (!valid[r]) continue;            // uniform across the wave
            const float* xr = X + (size_t)rows[r] * 128;
            const float* wa = W + (size_t)i1[r] * 128;
            const float* wb = W + (size_t)i2[r] * 128;
            double d1 = 0.0, d2 = 0.0;
            #pragma unroll
            for (int j = 0; j < 2; ++j) {
                const int d = lane * 2 + j;
                double xv = (double)xr[d];
                double e1 = xv - (double)wa[d]; d1 = fma(e1, e1, d1);
                double e2 = xv - (double)wb[d]; d2 = fma(e2, e2, d2);
            }
            #pragma unroll
            for (int off = 1; off < 64; off <<= 1) {
                d1 += __shfl_xor(d1, off, 64);
                d2 += __shfl_xor(d2, off, 64);
            }
            if (lane == 0) {
                int win; double dw;
                if (d1 < d2 || (d1 == d2 && i1[r] < i2[r])) { win = i1[r]; dw = d1; }
                else                                        { win = i2[r]; dw = d2; }
                cl_out[rows[r]] = (float)win;
                atomicAdd(inertia_acc, dw);
            }
        }
    }
}

// ---------------- fallback (3-pass bf16 in-kernel conversion, ws too small) --
__global__ __launch_bounds__(512, 1)
void dist_argmin_v2(const float* __restrict__ X, const float* __restrict__ W,
                    const float* __restrict__ w2g, float* __restrict__ cl_out,
                    double* __restrict__ inertia_acc,
                    int* __restrict__ flag_cnt, int* __restrict__ flag_rows,
                    int flag_cap)
{
    __shared__ __align__(16) char smem[133760];
    short*  Areg = (short*)smem;
    short*  Breg = (short*)(smem + 65536);
    int*    mscr = (int*)(smem + 131072);
    float*  lx2  = (float*)(smem + 131072 + 2048);
    double* dred = (double*)(smem + 131072 + 2048 + 512);

    const int tid    = threadIdx.x;
    const int lane   = tid & 63;
    const int laneLo = lane & 15;
    const int laneHi = lane >> 4;
    const int wid    = tid >> 6;
    const int rowg   = wid >> 1;
    const int colg   = wid & 1;
    const int rowbase = blockIdx.x * 128;

    {
        const int r = tid >> 2, q = tid & 3;
        float s = 0.f;
        #pragma unroll
        for (int j = 0; j < 8; ++j) {
            const int d0 = q * 4 + j * 16;
            float4 v = *reinterpret_cast<const float4*>(X + (size_t)(rowbase + r) * 128 + d0);
            float fv[4] = {v.x, v.y, v.z, v.w};
            s16x4 hv, lv;
            #pragma unroll
            for (int u = 0; u < 4; ++u) {
                s = fmaf(fv[u], fv[u], s);
                short h = f2bf_trunc(fv[u]);
                short l = f2bf_trunc(fv[u] - bf2f(h));
                hv[u] = h; lv[u] = l;
            }
            const int kb = d0 >> 3, off = d0 & 7;
            short* pa = Areg + (kb * 128 + r) * 8 + off;
            *reinterpret_cast<s16x4*>(pa)         = hv;
            *reinterpret_cast<s16x4*>(pa + 16384) = lv;
        }
        s += __shfl_xor(s, 1, 64);
        s += __shfl_xor(s, 2, 64);
        if (q == 0) lx2[r] = s;
    }

    float t1v[2][4], t2v[2][4];
    int   t1i[2][4];
    #pragma unroll
    for (int m = 0; m < 2; ++m)
        #pragma unroll
        for (int r = 0; r < 4; ++r) {
            t1v[m][r] = FLT_MAX; t2v[m][r] = FLT_MAX; t1i[m][r] = INT_MAX;
        }

    const char* pAbase = smem + laneHi * 2048 + (rowg * 32 + laneLo) * 16;
    const char* pBbase = smem + 65536 + colg * 16384 + lane * 16;

    for (int iter = 0; iter < 8; ++iter) {
        __syncthreads();
        {
            const int c = tid >> 2, q = tid & 3;
            const int nt = c >> 4, c15 = c & 15;
            #pragma unroll
            for (int j = 0; j < 8; ++j) {
                const int d0 = q * 4 + j * 16;
                float4 v = *reinterpret_cast<const float4*>(W + (size_t)(iter * 128 + c) * 128 + d0);
                float fv[4] = {v.x, v.y, v.z, v.w};
                s16x4 hv, lv;
                #pragma unroll
                for (int u = 0; u < 4; ++u) {
                    short h = f2bf_trunc(fv[u]);
                    short l = f2bf_trunc(fv[u] - bf2f(h));
                    hv[u] = h; lv[u] = l;
                }
                const int k0b = d0 >> 5, sub = (d0 >> 3) & 3, jj = d0 & 7;
                short* pb = Breg + ((nt * 4 + k0b) * 64 + sub * 16 + c15) * 8 + jj;
                *reinterpret_cast<s16x4*>(pb)         = hv;
                *reinterpret_cast<s16x4*>(pb + 16384) = lv;
            }
        }
        float w2v[4];
        #pragma unroll
        for (int nt = 0; nt < 4; ++nt)
            w2v[nt] = w2g[iter * 128 + colg * 64 + nt * 16 + laneLo];
        __syncthreads();

        f32x4 acc[2][4];
        #pragma unroll
        for (int m = 0; m < 2; ++m)
            #pragma unroll
            for (int nt = 0; nt < 4; ++nt)
                acc[m][nt] = (f32x4){0.f, 0.f, 0.f, 0.f};

        #pragma unroll
        for (int k0b = 0; k0b < 4; ++k0b) {
            bf16x8 ah[2], al[2];
            #pragma unroll
            for (int m = 0; m < 2; ++m) {
                ah[m] = *reinterpret_cast<const bf16x8*>(pAbase + k0b * 8192 + m * 256);
                al[m] = *reinterpret_cast<const bf16x8*>(pAbase + 32768 + k0b * 8192 + m * 256);
            }
            #pragma unroll
            for (int nt = 0; nt < 4; ++nt) {
                bf16x8 bh = *reinterpret_cast<const bf16x8*>(pBbase + nt * 4096 + k0b * 1024);
                bf16x8 bl = *reinterpret_cast<const bf16x8*>(pBbase + 32768 + nt * 4096 + k0b * 1024);
                #pragma unroll
                for (int m = 0; m < 2; ++m) {
                    acc[m][nt] = __builtin_amdgcn_mfma_f32_16x16x32_bf16(ah[m], bh, acc[m][nt], 0, 0, 0);
                    acc[m][nt] = __builtin_amdgcn_mfma_f32_16x16x32_bf16(ah[m], bl, acc[m][nt], 0, 0, 0);
                    acc[m][nt] = __builtin_amdgcn_mfma_f32_16x16x32_bf16(al[m], bh, acc[m][nt], 0, 0, 0);
                }
            }
        }

        #pragma unroll
        for (int nt = 0; nt < 4; ++nt) {
            const int col = iter * 128 + colg * 64 + nt * 16 + laneLo;
            #pragma unroll
            for (int m = 0; m < 2; ++m)
                #pragma unroll
                for (int r = 0; r < 4; ++r) {
                    float dv = fmaf(-2.f, acc[m][nt][r], w2v[nt]);
                    float hi = fmaxf(t1v[m][r], dv);
                    t2v[m][r] = fminf(t2v[m][r], hi);
                    bool cnd = dv < t1v[m][r];
                    t1i[m][r] = cnd ? col : t1i[m][r];
                    t1v[m][r] = fminf(t1v[m][r], dv);
                }
        }
    }

    #pragma unroll
    for (int off = 1; off < 16; off <<= 1) {
        #pragma unroll
        for (int m = 0; m < 2; ++m)
            #pragma unroll
            for (int r = 0; r < 4; ++r) {
                float ov1 = __shfl_xor(t1v[m][r], off, 64);
                int   oi1 = __shfl_xor(t1i[m][r], off, 64);
                float ov2 = __shfl_xor(t2v[m][r], off, 64);
                float nt2 = fminf(fminf(t2v[m][r], ov2), fmaxf(t1v[m][r], ov1));
                if (lexlt(ov1, oi1, t1v[m][r], t1i[m][r])) { t1v[m][r] = ov1; t1i[m][r] = oi1; }
                t2v[m][r] = nt2;
            }
    }

    __syncthreads();
    if (colg == 1 && laneLo == 0) {
        #pragma unroll
        for (int m = 0; m < 2; ++m)
            #pragma unroll
            for (int r = 0; r < 4; ++r) {
                const int row = rowg * 32 + m * 16 + laneHi * 4 + r;
                mscr[row * 4 + 0] = __float_as_int(t1v[m][r]);
                mscr[row * 4 + 1] = t1i[m][r];
                mscr[row * 4 + 2] = __float_as_int(t2v[m][r]);
            }
    }
    __syncthreads();
    double local = 0.0;
    if (colg == 0 && laneLo == 0) {
        #pragma unroll
        for (int m = 0; m < 2; ++m)
            #pragma unroll
            for (int r = 0; r < 4; ++r) {
                const int row = rowg * 32 + m * 16 + laneHi * 4 + r;
                float ov1 = __int_as_float(mscr[row * 4 + 0]);
                int   oi1 = mscr[row * 4 + 1];
                float ov2 = __int_as_float(mscr[row * 4 + 2]);
                float b1v = t1v[m][r], b2v;
                int   b1i = t1i[m][r];
                b2v = fminf(fminf(t2v[m][r], ov2), fmaxf(b1v, ov1));
                if (lexlt(ov1, oi1, b1v, b1i)) { b1v = ov1; b1i = oi1; }
                const int grow = rowbase + row;
                if (b2v - b1v < 1e-3f) {
                    int slot = atomicAdd(flag_cnt, 1);
                    if (slot < flag_cap) flag_rows[slot] = grow;
                    else { cl_out[grow] = (float)b1i; local += (double)(b1v + lx2[row]); }
                } else {
                    cl_out[grow] = (float)b1i;
                    local += (double)(b1v + lx2[row]);
                }
            }
        dred[rowg * 4 + laneHi] = local;
    }
    __syncthreads();
    if (tid == 0) {
        double t = 0.0;
        for (int i = 0; i < 16; ++i) t += dred[i];
        atomicAdd(inertia_acc, t);
    }
}

__global__ void finalize_kernel(const float* __restrict__ W, const float* __restrict__ w2,
                                const double* __restrict__ inertia, float* __restrict__ out)
{
    __shared__ float sh1[128], sh2[128];
    int d = threadIdx.x;                       // 128 threads
    float s = 0.f;
    for (int k = 0; k < 1024; ++k) s += W[(size_t)k * 128 + d];
    float t = 0.f;
    for (int j = 0; j < 8; ++j) t += w2[d + 128 * j];
    sh1[d] = s * s;
    sh2[d] = t;
    __syncthreads();
    for (int off = 64; off > 0; off >>= 1) {
        if (d < off) { sh1[d] += sh1[d + off]; sh2[d] += sh2[d + off]; }
        __syncthreads();
    }
    if (d == 0) {
        float xe = 2.f * sh2[0] - sh1[0];      // 2*trace(G) - sum(G)
        out[1] = xe / 1024.f;
        out[0] = (float)(*inertia / 131072.0);
    }
}

extern "C" void kernel_launch(void* const* d_in, const int* in_sizes, int n_in,
                              void* d_out, int out_size, void* d_ws, size_t ws_size,
                              hipStream_t stream)
{
    const float* X = (const float*)d_in[0];          // [131072,128] f32
    const float* W = (const float*)d_in[1];          // [1024,128]   f32
    float* out = (float*)d_out;                       // [131074]     f32
    char* ws = (char*)d_ws;

    double* inertia  = (double*)ws;
    int*    flag_cnt = (int*)(ws + 8);
    float*  w2       = (float*)(ws + 16);
    short*  wh       = (short*)(ws + 4608);
    int*    flags    = (int*)(ws + 266752);
    const int FCAP = 32768;
    const size_t NEED = 397824;

    const bool precomp = ws_size >= NEED;

    hipMemsetAsync(ws, 0, 16, stream);               // inertia + flag_cnt

    if (precomp) {
        wprep_kernel<<<1024, 128, 0, stream>>>(W, w2, wh, 1);
        dist_argmin_1p<<<1024, 512, 0, stream>>>(X, wh, w2, out + 2, inertia,
                                                 flag_cnt, flags, FCAP);
        refine_kernel<<<512, 256, 0, stream>>>(X, W, w2, flag_cnt, flags, FCAP,
                                               out + 2, inertia);
    } else {
        int* flagsf = (int*)(ws + 4608);
        long cap = ((long)ws_size - 4608) / 4;
        int capf = cap < 0 ? 0 : (cap > 131072 ? 131072 : (int)cap);
        wprep_kernel<<<1024, 128, 0, stream>>>(W, w2, (short*)flagsf, 0);
        dist_argmin_v2<<<1024, 512, 0, stream>>>(X, W, w2, out + 2, inertia,
                                                 flag_cnt, flagsf, capf);
        refine_kernel<<<512, 256, 0, stream>>>(X, W, w2, flag_cnt, flagsf, capf,
                                               out + 2, inertia);
    }
    finalize_kernel<<<1, 128, 0, stream>>>(W, w2, inertia, out);
}

// Round 11
// 238.337 us; speedup vs baseline: 1.0985x; 1.0985x over previous
//
#include <hip/hip_runtime.h>
#include <float.h>
#include <limits.h>
#include <math.h>

// ClusterLayer: B=131072 rows, K=1024 clusters, D=128.
// out (float32): [0] inertia/B, [1] xe/K, [2..2+B) cl as float.
//
// R11: dist = R9/R10's 1-pass RNE-fp16 MFMA (lean tracker, counted-vmcnt
// dbuf), TAU=2.5e-3 (R9-validated). refine = R10's coalesced 4-row/wave
// rescan + per-block inertia reduction (one atomic per block, not per row).
//
// ws layout (bytes):
//   0      : double inertia_acc
//   8      : int    flag_cnt
//   16     : float  w2[1024]
//   4608   : short  wh[131072]     (256 KB, fp16-RNE W, tile fragment order)
//   266752 : int    flag_rows[32768]  -> end 397824

#define TAU 2.5e-3f

using f16x8  = __attribute__((ext_vector_type(8))) _Float16;
using bf16x8 = __attribute__((ext_vector_type(8))) short;
using f32x4  = __attribute__((ext_vector_type(4))) float;
using s16x4  = __attribute__((ext_vector_type(4))) short;

static __device__ __forceinline__ short f2bf_trunc(float f) {
    return (short)(__float_as_uint(f) >> 16);
}
static __device__ __forceinline__ float bf2f(short h) {
    return __uint_as_float(((unsigned int)(unsigned short)h) << 16);
}
static __device__ __forceinline__ bool lexlt(float v1, int i1, float v2, int i2) {
    return v1 < v2 || (v1 == v2 && i1 < i2);
}
static __device__ __forceinline__ void gload_lds16(const void* g, void* l) {
    __builtin_amdgcn_global_load_lds(
        (const __attribute__((address_space(1))) unsigned int*)g,
        (__attribute__((address_space(3))) unsigned int*)l, 16, 0, 0);
}
#define FENCE() do { asm volatile("" ::: "memory"); __builtin_amdgcn_sched_barrier(0); } while (0)

// W prep: w2 per cluster (f32-exact) + fp16-RNE image in 64-col-tile fragment
// order: shorts: tile*8192 + (c>>4)*2048 + (d>>5)*512 + ((d>>3)&3)*128
//                + (c&15)*8 + (d&7);   tile=k>>6, c=k&63
__global__ void wprep_kernel(const float* __restrict__ W, float* __restrict__ w2,
                             short* __restrict__ wh, int write_wh)
{
    const int k = blockIdx.x;
    const int d = threadIdx.x;     // 0..127
    float v = W[(size_t)k * 128 + d];
    float sq = v * v;
    for (int off = 1; off < 64; off <<= 1) sq += __shfl_xor(sq, off, 64);
    __shared__ float p[2];
    if ((d & 63) == 0) p[d >> 6] = sq;
    __syncthreads();
    if (d == 0) w2[k] = p[0] + p[1];
    if (write_wh) {
        _Float16 h = (_Float16)v;                       // RNE
        const int tile = k >> 6, c = k & 63;
        size_t base = (size_t)tile * 8192 + (size_t)(c >> 4) * 2048 + (size_t)(d >> 5) * 512
                    + (size_t)((d >> 3) & 3) * 128 + (size_t)(c & 15) * 8 + (size_t)(d & 7);
        wh[base] = *reinterpret_cast<short*>(&h);
    }
}

// LDS (bytes): lB0 0..32768 | lB1 32768..65536 | lw2 65536..69632 |
//              lx2 69632..70144 | mscr 70144..72192 (128 x 4 ints) |
//              dred 72192..72320
__global__ __launch_bounds__(512, 4)
void dist_argmin_1p(const float* __restrict__ X, const short* __restrict__ wh,
                    const float* __restrict__ w2g, float* __restrict__ cl_out,
                    double* __restrict__ inertia_acc,
                    int* __restrict__ flag_cnt, int* __restrict__ flag_rows,
                    int flag_cap)
{
    __shared__ __align__(16) char smem[72320];
    char*   lB0  = smem;
    char*   lB1  = smem + 32768;
    float*  lw2  = (float*)(smem + 65536);
    float*  lx2  = (float*)(smem + 69632);
    int*    mscr = (int*)(smem + 70144);
    double* dred = (double*)(smem + 72192);

    const int tid    = threadIdx.x;
    const int lane   = tid & 63;
    const int laneLo = lane & 15;
    const int laneHi = lane >> 4;
    const int wid    = tid >> 6;
    const int rowg   = wid >> 1;
    const int colg   = wid & 1;
    const int rowbase = blockIdx.x * 128;

    // w2 -> LDS (K-loop must have zero global loads so vmcnt counting holds)
    lw2[tid]       = w2g[tid];
    lw2[tid + 512] = w2g[tid + 512];

    // ---- A (fp16 RNE) straight from global into registers + ||x||^2 ----
    f16x8 ah[2][4];
    #pragma unroll
    for (int m = 0; m < 2; ++m) {
        const float* xp = X + (size_t)(rowbase + rowg * 32 + m * 16 + laneLo) * 128 + laneHi * 8;
        float s = 0.f;
        #pragma unroll
        for (int k0b = 0; k0b < 4; ++k0b) {
            float4 v0 = *reinterpret_cast<const float4*>(xp + k0b * 32);
            float4 v1 = *reinterpret_cast<const float4*>(xp + k0b * 32 + 4);
            float fv[8] = {v0.x, v0.y, v0.z, v0.w, v1.x, v1.y, v1.z, v1.w};
            f16x8 hv;
            #pragma unroll
            for (int u = 0; u < 8; ++u) {
                s = fmaf(fv[u], fv[u], s);
                hv[u] = (_Float16)fv[u];               // RNE
            }
            ah[m][k0b] = hv;
        }
        s += __shfl_xor(s, 16, 64);     // combine 4 laneHi dim-slices
        s += __shfl_xor(s, 32, 64);
        if (colg == 0 && laneHi == 0) lx2[rowg * 32 + m * 16 + laneLo] = s;
    }

    // ---- issue phase 0 DMA -> lB0 (32 KB = 128 clusters; 4 x 16B/thread) ----
    #pragma unroll
    for (int q = 0; q < 4; ++q)
        gload_lds16((const char*)wh + wid * 4096 + q * 1024 + lane * 16,
                    lB0 + wid * 4096 + q * 1024);

    // drain my lw2/lx2 ds_writes before the first in-loop barrier
    asm volatile("s_waitcnt lgkmcnt(0)" ::: "memory");
    __builtin_amdgcn_sched_barrier(0);

    float t1v[2][4], t2v[2][4];
    int   t1i[2][4];
    #pragma unroll
    for (int m = 0; m < 2; ++m)
        #pragma unroll
        for (int r = 0; r < 4; ++r) {
            t1v[m][r] = FLT_MAX; t2v[m][r] = FLT_MAX; t1i[m][r] = INT_MAX;
        }

    // one 16KB tile = 64 clusters; ti = global tile index (0..15)
    auto compute = [&](int ti, const char* tileBase) {
        const char* pBb = tileBase + colg * 8192 + lane * 16;
        float w2v[2];
        #pragma unroll
        for (int nt = 0; nt < 2; ++nt)
            w2v[nt] = lw2[ti * 64 + colg * 32 + nt * 16 + laneLo];

        __builtin_amdgcn_s_setprio(1);
        #pragma unroll
        for (int nt = 0; nt < 2; ++nt) {
            f32x4 a0 = (f32x4){0.f, 0.f, 0.f, 0.f};
            f32x4 a1 = (f32x4){0.f, 0.f, 0.f, 0.f};
            #pragma unroll
            for (int k0b = 0; k0b < 4; ++k0b) {
                f16x8 bh = *reinterpret_cast<const f16x8*>(pBb + nt * 4096 + k0b * 1024);
                a0 = __builtin_amdgcn_mfma_f32_16x16x32_f16(ah[0][k0b], bh, a0, 0, 0, 0);
                a1 = __builtin_amdgcn_mfma_f32_16x16x32_f16(ah[1][k0b], bh, a1, 0, 0, 0);
            }
            // dist = w2 - 2*dot_f16; branch-free top-2 values + top-1 index.
            const int col = ti * 64 + colg * 32 + nt * 16 + laneLo;
            #pragma unroll
            for (int r = 0; r < 4; ++r) {
                float dv0 = fmaf(-2.f, a0[r], w2v[nt]);
                t2v[0][r] = fminf(t2v[0][r], fmaxf(t1v[0][r], dv0));
                t1i[0][r] = (dv0 < t1v[0][r]) ? col : t1i[0][r];
                t1v[0][r] = fminf(t1v[0][r], dv0);
                float dv1 = fmaf(-2.f, a1[r], w2v[nt]);
                t2v[1][r] = fminf(t2v[1][r], fmaxf(t1v[1][r], dv1));
                t1i[1][r] = (dv1 < t1v[1][r]) ? col : t1i[1][r];
                t1v[1][r] = fminf(t1v[1][r], dv1);
            }
        }
        __builtin_amdgcn_s_setprio(0);
    };

    const char* cur = lB0;
    char*       nxt = lB1;
    #pragma unroll 1
    for (int p = 0; p < 8; ++p) {
        if (p < 7) {
            const char* src = (const char*)wh + (size_t)(p + 1) * 32768;
            #pragma unroll
            for (int q = 0; q < 4; ++q)
                gload_lds16(src + wid * 4096 + q * 1024 + lane * 16,
                            nxt + wid * 4096 + q * 1024);
            asm volatile("s_waitcnt vmcnt(4)" ::: "memory");  // phase p landed; p+1 in flight
        } else {
            asm volatile("s_waitcnt vmcnt(0)" ::: "memory");
        }
        __builtin_amdgcn_sched_barrier(0);
        __builtin_amdgcn_s_barrier();                         // everyone's phase p landed
        FENCE();
        compute(2 * p,     cur);
        compute(2 * p + 1, cur + 16384);
        if (p < 7) {
            asm volatile("s_waitcnt lgkmcnt(0)" ::: "memory");
            __builtin_amdgcn_sched_barrier(0);
            __builtin_amdgcn_s_barrier();                     // all waves done reading cur
            FENCE();
            char* tmp = nxt; nxt = (char*)cur; cur = tmp;
        }
    }

    // ---- reduce top-2 across the 16 col-lanes (laneLo) of each row ----
    #pragma unroll
    for (int off = 1; off < 16; off <<= 1) {
        #pragma unroll
        for (int m = 0; m < 2; ++m)
            #pragma unroll
            for (int r = 0; r < 4; ++r) {
                float ov1 = __shfl_xor(t1v[m][r], off, 64);
                int   oi1 = __shfl_xor(t1i[m][r], off, 64);
                float ov2 = __shfl_xor(t2v[m][r], off, 64);
                float nt2 = fminf(fminf(t2v[m][r], ov2), fmaxf(t1v[m][r], ov1));
                if (lexlt(ov1, oi1, t1v[m][r], t1i[m][r])) { t1v[m][r] = ov1; t1i[m][r] = oi1; }
                t2v[m][r] = nt2;
            }
    }

    // ---- merge col-halves via LDS ----
    __syncthreads();
    if (colg == 1 && laneLo == 0) {
        #pragma unroll
        for (int m = 0; m < 2; ++m)
            #pragma unroll
            for (int r = 0; r < 4; ++r) {
                const int row = rowg * 32 + m * 16 + laneHi * 4 + r;
                mscr[row * 4 + 0] = __float_as_int(t1v[m][r]);
                mscr[row * 4 + 1] = t1i[m][r];
                mscr[row * 4 + 2] = __float_as_int(t2v[m][r]);
            }
    }
    __syncthreads();
    double local = 0.0;
    if (colg == 0 && laneLo == 0) {
        #pragma unroll
        for (int m = 0; m < 2; ++m)
            #pragma unroll
            for (int r = 0; r < 4; ++r) {
                const int row = rowg * 32 + m * 16 + laneHi * 4 + r;
                float ov1 = __int_as_float(mscr[row * 4 + 0]);
                int   oi1 = mscr[row * 4 + 1];
                float ov2 = __int_as_float(mscr[row * 4 + 2]);
                float b1v = t1v[m][r], b2v;
                int   b1i = t1i[m][r];
                b2v = fminf(fminf(t2v[m][r], ov2), fmaxf(b1v, ov1));
                if (lexlt(ov1, oi1, b1v, b1i)) { b1v = ov1; b1i = oi1; }
                const int grow = rowbase + row;
                if (b2v - b1v < TAU) {                 // near-tie: exact rescan
                    int slot = atomicAdd(flag_cnt, 1);
                    if (slot < flag_cap) {
                        flag_rows[slot] = grow;
                    } else {
                        cl_out[grow] = (float)b1i;
                        local += (double)(b1v + lx2[row]);
                    }
                } else {
                    cl_out[grow] = (float)b1i;
                    local += (double)(b1v + lx2[row]);
                }
            }
        dred[rowg * 4 + laneHi] = local;
    }
    __syncthreads();
    if (tid == 0) {
        double tt = 0.0;
        for (int i = 0; i < 16; ++i) tt += dred[i];
        atomicAdd(inertia_acc, tt);
    }
}

// refine: one WAVE per group of 4 flagged rows. lane=(cgrp,kpart):
// kpart=lane&7 owns dims kpart*16..+16 (contiguous -> coalesced W/X reads),
// cgrp=lane>>3 owns clusters cgrp*128..+128. W read once per 4 rows.
// f32 rescan -> top-2 (lexicographic) -> 64-lane-parallel exact f64 pair.
// Inertia: accumulated per wave, reduced per block, ONE atomic per block.
__global__ __launch_bounds__(256)
void refine_kernel(const float* __restrict__ X, const float* __restrict__ W,
                   const float* __restrict__ w2,
                   const int* __restrict__ flag_cnt,
                   const int* __restrict__ flag_rows, int flag_cap,
                   float* __restrict__ cl_out, double* __restrict__ inertia_acc)
{
    __shared__ double bred[4];
    int n = *flag_cnt;
    if (n > flag_cap) n = flag_cap;
    const int lane  = threadIdx.x & 63;
    const int wv    = threadIdx.x >> 6;
    const int kpart = lane & 7;       // contiguous dim segment -> coalesced
    const int cgrp  = lane >> 3;      // 0..7

    double wacc = 0.0;                // per-wave (lane0-held) inertia partial

    const int ngroups = (n + 3) >> 2;
    for (int g = blockIdx.x * 4 + wv; g < ngroups; g += gridDim.x * 4) {
        int  rows[4];
        bool valid[4];
        #pragma unroll
        for (int r = 0; r < 4; ++r) {
            const int f = g * 4 + r;
            valid[r] = (f < n);
            rows[r]  = flag_rows[valid[r] ? f : (n - 1)];
        }
        // 4 X-row segments (16 floats each) in registers
        float4 xa[4][4];
        #pragma unroll
        for (int r = 0; r < 4; ++r) {
            const float* xk = X + (size_t)rows[r] * 128 + kpart * 16;
            xa[r][0] = *reinterpret_cast<const float4*>(xk);
            xa[r][1] = *reinterpret_cast<const float4*>(xk + 4);
            xa[r][2] = *reinterpret_cast<const float4*>(xk + 8);
            xa[r][3] = *reinterpret_cast<const float4*>(xk + 12);
        }

        float v1[4], v2[4];
        int   i1[4], i2[4];
        #pragma unroll
        for (int r = 0; r < 4; ++r) { v1[r] = FLT_MAX; v2[r] = FLT_MAX; i1[r] = INT_MAX; i2[r] = INT_MAX; }

        #pragma unroll 2
        for (int q = 0; q < 128; ++q) {
            const int c = cgrp * 128 + q;
            const float* wr = W + (size_t)c * 128 + kpart * 16;
            float4 w0 = *reinterpret_cast<const float4*>(wr);
            float4 w1 = *reinterpret_cast<const float4*>(wr + 4);
            float4 w2f = *reinterpret_cast<const float4*>(wr + 8);
            float4 w3 = *reinterpret_cast<const float4*>(wr + 12);
            const float w2c = w2[c];
            #pragma unroll
            for (int r = 0; r < 4; ++r) {
                float p0 = fmaf(xa[r][0].w, w0.w, fmaf(xa[r][0].z, w0.z, fmaf(xa[r][0].y, w0.y, xa[r][0].x * w0.x)));
                float p1 = fmaf(xa[r][1].w, w1.w, fmaf(xa[r][1].z, w1.z, fmaf(xa[r][1].y, w1.y, xa[r][1].x * w1.x)));
                float p2 = fmaf(xa[r][2].w, w2f.w, fmaf(xa[r][2].z, w2f.z, fmaf(xa[r][2].y, w2f.y, xa[r][2].x * w2f.x)));
                float p3 = fmaf(xa[r][3].w, w3.w, fmaf(xa[r][3].z, w3.z, fmaf(xa[r][3].y, w3.y, xa[r][3].x * w3.x)));
                float p = (p0 + p1) + (p2 + p3);
                p += __shfl_xor(p, 1, 64);      // reduce over kpart (lane&7)
                p += __shfl_xor(p, 2, 64);
                p += __shfl_xor(p, 4, 64);
                float dv = fmaf(-2.f, p, w2c);
                if (dv < v1[r]) { v2[r] = v1[r]; i2[r] = i1[r]; v1[r] = dv; i1[r] = c; }  // c ascending
                else if (dv < v2[r]) { v2[r] = dv; i2[r] = c; }
            }
        }
        // merge top-2 across the 8 cgrps (xor 8,16,32)
        #pragma unroll
        for (int off = 8; off < 64; off <<= 1) {
            #pragma unroll
            for (int r = 0; r < 4; ++r) {
                float ov1 = __shfl_xor(v1[r], off, 64);
                int   oi1 = __shfl_xor(i1[r], off, 64);
                float ov2 = __shfl_xor(v2[r], off, 64);
                int   oi2 = __shfl_xor(i2[r], off, 64);
                if (lexlt(ov1, oi1, v1[r], i1[r])) {
                    float nv2; int ni2;
                    if (lexlt(v1[r], i1[r], ov2, oi2)) { nv2 = v1[r]; ni2 = i1[r]; }
                    else                               { nv2 = ov2;   ni2 = oi2; }
                    v1[r] = ov1; i1[r] = oi1; v2[r] = nv2; i2[r] = ni2;
                } else if (lexlt(ov1, oi1, v2[r], i2[r])) {
                    v2[r] = ov1; i2[r] = oi1;
                }
            }
        }
        // exact f64 pair decision per row, parallel over 64 lanes (2 dims each)
        #pragma unroll
        for (int r = 0; r < 4; ++r) {
            if (!valid[r]) continue;            // uniform across the wave
            const float* xr = X + (size_t)rows[r] * 128;
            const float* wa = W + (size_t)i1[r] * 128;
            const float* wb = W + (size_t)i2[r] * 128;
            double d1 = 0.0, d2 = 0.0;
            #pragma unroll
            for (int j = 0; j < 2; ++j) {
                const int d = lane * 2 + j;
                double xv = (double)xr[d];
                double e1 = xv - (double)wa[d]; d1 = fma(e1, e1, d1);
                double e2 = xv - (double)wb[d]; d2 = fma(e2, e2, d2);
            }
            #pragma unroll
            for (int off = 1; off < 64; off <<= 1) {
                d1 += __shfl_xor(d1, off, 64);
                d2 += __shfl_xor(d2, off, 64);
            }
            if (lane == 0) {
                int win; double dw;
                if (d1 < d2 || (d1 == d2 && i1[r] < i2[r])) { win = i1[r]; dw = d1; }
                else                                        { win = i2[r]; dw = d2; }
                cl_out[rows[r]] = (float)win;
                wacc += dw;
            }
        }
    }

    // per-block inertia reduction: one atomic per block (Guideline 12)
    if (lane == 0) bred[wv] = wacc;
    __syncthreads();
    if (threadIdx.x == 0) {
        double t = bred[0] + bred[1] + bred[2] + bred[3];
        if (t != 0.0) atomicAdd(inertia_acc, t);
    }
}

// ---------------- fallback (3-pass bf16 in-kernel conversion, ws too small) --
__global__ __launch_bounds__(512, 1)
void dist_argmin_v2(const float* __restrict__ X, const float* __restrict__ W,
                    const float* __restrict__ w2g, float* __restrict__ cl_out,
                    double* __restrict__ inertia_acc,
                    int* __restrict__ flag_cnt, int* __restrict__ flag_rows,
                    int flag_cap)
{
    __shared__ __align__(16) char smem[133760];
    short*  Areg = (short*)smem;
    short*  Breg = (short*)(smem + 65536);
    int*    mscr = (int*)(smem + 131072);
    float*  lx2  = (float*)(smem + 131072 + 2048);
    double* dred = (double*)(smem + 131072 + 2048 + 512);

    const int tid    = threadIdx.x;
    const int lane   = tid & 63;
    const int laneLo = lane & 15;
    const int laneHi = lane >> 4;
    const int wid    = tid >> 6;
    const int rowg   = wid >> 1;
    const int colg   = wid & 1;
    const int rowbase = blockIdx.x * 128;

    {
        const int r = tid >> 2, q = tid & 3;
        float s = 0.f;
        #pragma unroll
        for (int j = 0; j < 8; ++j) {
            const int d0 = q * 4 + j * 16;
            float4 v = *reinterpret_cast<const float4*>(X + (size_t)(rowbase + r) * 128 + d0);
            float fv[4] = {v.x, v.y, v.z, v.w};
            s16x4 hv, lv;
            #pragma unroll
            for (int u = 0; u < 4; ++u) {
                s = fmaf(fv[u], fv[u], s);
                short h = f2bf_trunc(fv[u]);
                short l = f2bf_trunc(fv[u] - bf2f(h));
                hv[u] = h; lv[u] = l;
            }
            const int kb = d0 >> 3, off = d0 & 7;
            short* pa = Areg + (kb * 128 + r) * 8 + off;
            *reinterpret_cast<s16x4*>(pa)         = hv;
            *reinterpret_cast<s16x4*>(pa + 16384) = lv;
        }
        s += __shfl_xor(s, 1, 64);
        s += __shfl_xor(s, 2, 64);
        if (q == 0) lx2[r] = s;
    }

    float t1v[2][4], t2v[2][4];
    int   t1i[2][4];
    #pragma unroll
    for (int m = 0; m < 2; ++m)
        #pragma unroll
        for (int r = 0; r < 4; ++r) {
            t1v[m][r] = FLT_MAX; t2v[m][r] = FLT_MAX; t1i[m][r] = INT_MAX;
        }

    const char* pAbase = smem + laneHi * 2048 + (rowg * 32 + laneLo) * 16;
    const char* pBbase = smem + 65536 + colg * 16384 + lane * 16;

    for (int iter = 0; iter < 8; ++iter) {
        __syncthreads();
        {
            const int c = tid >> 2, q = tid & 3;
            const int nt = c >> 4, c15 = c & 15;
            #pragma unroll
            for (int j = 0; j < 8; ++j) {
                const int d0 = q * 4 + j * 16;
                float4 v = *reinterpret_cast<const float4*>(W + (size_t)(iter * 128 + c) * 128 + d0);
                float fv[4] = {v.x, v.y, v.z, v.w};
                s16x4 hv, lv;
                #pragma unroll
                for (int u = 0; u < 4; ++u) {
                    short h = f2bf_trunc(fv[u]);
                    short l = f2bf_trunc(fv[u] - bf2f(h));
                    hv[u] = h; lv[u] = l;
                }
                const int k0b = d0 >> 5, sub = (d0 >> 3) & 3, jj = d0 & 7;
                short* pb = Breg + ((nt * 4 + k0b) * 64 + sub * 16 + c15) * 8 + jj;
                *reinterpret_cast<s16x4*>(pb)         = hv;
                *reinterpret_cast<s16x4*>(pb + 16384) = lv;
            }
        }
        float w2v[4];
        #pragma unroll
        for (int nt = 0; nt < 4; ++nt)
            w2v[nt] = w2g[iter * 128 + colg * 64 + nt * 16 + laneLo];
        __syncthreads();

        f32x4 acc[2][4];
        #pragma unroll
        for (int m = 0; m < 2; ++m)
            #pragma unroll
            for (int nt = 0; nt < 4; ++nt)
                acc[m][nt] = (f32x4){0.f, 0.f, 0.f, 0.f};

        #pragma unroll
        for (int k0b = 0; k0b < 4; ++k0b) {
            bf16x8 ah[2], al[2];
            #pragma unroll
            for (int m = 0; m < 2; ++m) {
                ah[m] = *reinterpret_cast<const bf16x8*>(pAbase + k0b * 8192 + m * 256);
                al[m] = *reinterpret_cast<const bf16x8*>(pAbase + 32768 + k0b * 8192 + m * 256);
            }
            #pragma unroll
            for (int nt = 0; nt < 4; ++nt) {
                bf16x8 bh = *reinterpret_cast<const bf16x8*>(pBbase + nt * 4096 + k0b * 1024);
                bf16x8 bl = *reinterpret_cast<const bf16x8*>(pBbase + 32768 + nt * 4096 + k0b * 1024);
                #pragma unroll
                for (int m = 0; m < 2; ++m) {
                    acc[m][nt] = __builtin_amdgcn_mfma_f32_16x16x32_bf16(ah[m], bh, acc[m][nt], 0, 0, 0);
                    acc[m][nt] = __builtin_amdgcn_mfma_f32_16x16x32_bf16(ah[m], bl, acc[m][nt], 0, 0, 0);
                    acc[m][nt] = __builtin_amdgcn_mfma_f32_16x16x32_bf16(al[m], bh, acc[m][nt], 0, 0, 0);
                }
            }
        }

        #pragma unroll
        for (int nt = 0; nt < 4; ++nt) {
            const int col = iter * 128 + colg * 64 + nt * 16 + laneLo;
            #pragma unroll
            for (int m = 0; m < 2; ++m)
                #pragma unroll
                for (int r = 0; r < 4; ++r) {
                    float dv = fmaf(-2.f, acc[m][nt][r], w2v[nt]);
                    float hi = fmaxf(t1v[m][r], dv);
                    t2v[m][r] = fminf(t2v[m][r], hi);
                    bool cnd = dv < t1v[m][r];
                    t1i[m][r] = cnd ? col : t1i[m][r];
                    t1v[m][r] = fminf(t1v[m][r], dv);
                }
        }
    }

    #pragma unroll
    for (int off = 1; off < 16; off <<= 1) {
        #pragma unroll
        for (int m = 0; m < 2; ++m)
            #pragma unroll
            for (int r = 0; r < 4; ++r) {
                float ov1 = __shfl_xor(t1v[m][r], off, 64);
                int   oi1 = __shfl_xor(t1i[m][r], off, 64);
                float ov2 = __shfl_xor(t2v[m][r], off, 64);
                float nt2 = fminf(fminf(t2v[m][r], ov2), fmaxf(t1v[m][r], ov1));
                if (lexlt(ov1, oi1, t1v[m][r], t1i[m][r])) { t1v[m][r] = ov1; t1i[m][r] = oi1; }
                t2v[m][r] = nt2;
            }
    }

    __syncthreads();
    if (colg == 1 && laneLo == 0) {
        #pragma unroll
        for (int m = 0; m < 2; ++m)
            #pragma unroll
            for (int r = 0; r < 4; ++r) {
                const int row = rowg * 32 + m * 16 + laneHi * 4 + r;
                mscr[row * 4 + 0] = __float_as_int(t1v[m][r]);
                mscr[row * 4 + 1] = t1i[m][r];
                mscr[row * 4 + 2] = __float_as_int(t2v[m][r]);
            }
    }
    __syncthreads();
    double local = 0.0;
    if (colg == 0 && laneLo == 0) {
        #pragma unroll
        for (int m = 0; m < 2; ++m)
            #pragma unroll
            for (int r = 0; r < 4; ++r) {
                const int row = rowg * 32 + m * 16 + laneHi * 4 + r;
                float ov1 = __int_as_float(mscr[row * 4 + 0]);
                int   oi1 = mscr[row * 4 + 1];
                float ov2 = __int_as_float(mscr[row * 4 + 2]);
                float b1v = t1v[m][r], b2v;
                int   b1i = t1i[m][r];
                b2v = fminf(fminf(t2v[m][r], ov2), fmaxf(b1v, ov1));
                if (lexlt(ov1, oi1, b1v, b1i)) { b1v = ov1; b1i = oi1; }
                const int grow = rowbase + row;
                if (b2v - b1v < 1e-3f) {
                    int slot = atomicAdd(flag_cnt, 1);
                    if (slot < flag_cap) flag_rows[slot] = grow;
                    else { cl_out[grow] = (float)b1i; local += (double)(b1v + lx2[row]); }
                } else {
                    cl_out[grow] = (float)b1i;
                    local += (double)(b1v + lx2[row]);
                }
            }
        dred[rowg * 4 + laneHi] = local;
    }
    __syncthreads();
    if (tid == 0) {
        double t = 0.0;
        for (int i = 0; i < 16; ++i) t += dred[i];
        atomicAdd(inertia_acc, t);
    }
}

__global__ void finalize_kernel(const float* __restrict__ W, const float* __restrict__ w2,
                                const double* __restrict__ inertia, float* __restrict__ out)
{
    __shared__ float sh1[128], sh2[128];
    int d = threadIdx.x;                       // 128 threads
    float s = 0.f;
    for (int k = 0; k < 1024; ++k) s += W[(size_t)k * 128 + d];
    float t = 0.f;
    for (int j = 0; j < 8; ++j) t += w2[d + 128 * j];
    sh1[d] = s * s;
    sh2[d] = t;
    __syncthreads();
    for (int off = 64; off > 0; off >>= 1) {
        if (d < off) { sh1[d] += sh1[d + off]; sh2[d] += sh2[d + off]; }
        __syncthreads();
    }
    if (d == 0) {
        float xe = 2.f * sh2[0] - sh1[0];      // 2*trace(G) - sum(G)
        out[1] = xe / 1024.f;
        out[0] = (float)(*inertia / 131072.0);
    }
}

extern "C" void kernel_launch(void* const* d_in, const int* in_sizes, int n_in,
                              void* d_out, int out_size, void* d_ws, size_t ws_size,
                              hipStream_t stream)
{
    const float* X = (const float*)d_in[0];          // [131072,128] f32
    const float* W = (const float*)d_in[1];          // [1024,128]   f32
    float* out = (float*)d_out;                       // [131074]     f32
    char* ws = (char*)d_ws;

    double* inertia  = (double*)ws;
    int*    flag_cnt = (int*)(ws + 8);
    float*  w2       = (float*)(ws + 16);
    short*  wh       = (short*)(ws + 4608);
    int*    flags    = (int*)(ws + 266752);
    const int FCAP = 32768;
    const size_t NEED = 397824;

    const bool precomp = ws_size >= NEED;

    hipMemsetAsync(ws, 0, 16, stream);               // inertia + flag_cnt

    if (precomp) {
        wprep_kernel<<<1024, 128, 0, stream>>>(W, w2, wh, 1);
        dist_argmin_1p<<<1024, 512, 0, stream>>>(X, wh, w2, out + 2, inertia,
                                                 flag_cnt, flags, FCAP);
        refine_kernel<<<512, 256, 0, stream>>>(X, W, w2, flag_cnt, flags, FCAP,
                                               out + 2, inertia);
    } else {
        int* flagsf = (int*)(ws + 4608);
        long cap = ((long)ws_size - 4608) / 4;
        int capf = cap < 0 ? 0 : (cap > 131072 ? 131072 : (int)cap);
        wprep_kernel<<<1024, 128, 0, stream>>>(W, w2, (short*)flagsf, 0);
        dist_argmin_v2<<<1024, 512, 0, stream>>>(X, W, w2, out + 2, inertia,
                                                 flag_cnt, flagsf, capf);
        refine_kernel<<<512, 256, 0, stream>>>(X, W, w2, flag_cnt, flagsf, capf,
                                               out + 2, inertia);
    }
    finalize_kernel<<<1, 128, 0, stream>>>(W, w2, inertia, out);
}

// Round 12
// 198.324 us; speedup vs baseline: 1.3202x; 1.2018x over previous
//
#include <hip/hip_runtime.h>
#include <float.h>
#include <limits.h>
#include <math.h>

// ClusterLayer: B=131072 rows, K=1024 clusters, D=128.
// out (float32): [0] inertia/B, [1] xe/K, [2..2+B) cl as float.
//
// R12: zero same-address f64 atomics (the R8-R11 refine mystery: serialized
// device-scope atomicAdds ~60ns each). Inertia -> per-block ws slots summed
// in finalize. refine3 = block-per-row, W staged in padded LDS, full f32
// rescan + wave-parallel f64 pair. dist = R11's fp16 1-pass (proven).
//
// ws layout (bytes):
//   0      : double acc0              (fallback-path atomics only)
//   8      : int    flag_cnt
//   16     : float  w2[1024]                       -> 4112
//   4608   : double distSlots[1024]  (8 KB)        -> 12800
//   12800  : double refSlots[512]    (4 KB)        -> 16896
//   16896  : short  wh[262144]       (512 KB capacity; fp16 uses 256 KB)
//   541184 : int    flag_rows[16384]               -> 606720

#define TAU 2.5e-3f

using f16x8  = __attribute__((ext_vector_type(8))) _Float16;
using bf16x8 = __attribute__((ext_vector_type(8))) short;
using f32x4  = __attribute__((ext_vector_type(4))) float;
using s16x4  = __attribute__((ext_vector_type(4))) short;

static __device__ __forceinline__ short f2bf_trunc(float f) {
    return (short)(__float_as_uint(f) >> 16);
}
static __device__ __forceinline__ float bf2f(short h) {
    return __uint_as_float(((unsigned int)(unsigned short)h) << 16);
}
static __device__ __forceinline__ bool lexlt(float v1, int i1, float v2, int i2) {
    return v1 < v2 || (v1 == v2 && i1 < i2);
}
static __device__ __forceinline__ void gload_lds16(const void* g, void* l) {
    __builtin_amdgcn_global_load_lds(
        (const __attribute__((address_space(1))) unsigned int*)g,
        (__attribute__((address_space(3))) unsigned int*)l, 16, 0, 0);
}
#define FENCE() do { asm volatile("" ::: "memory"); __builtin_amdgcn_sched_barrier(0); } while (0)

// W prep: w2 per cluster (f32-exact) + fp16-RNE image in 64-col-tile fragment
// order: shorts: tile*8192 + (c>>4)*2048 + (d>>5)*512 + ((d>>3)&3)*128
//                + (c&15)*8 + (d&7);   tile=k>>6, c=k&63
__global__ void wprep_kernel(const float* __restrict__ W, float* __restrict__ w2,
                             short* __restrict__ wh, int write_wh)
{
    const int k = blockIdx.x;
    const int d = threadIdx.x;     // 0..127
    float v = W[(size_t)k * 128 + d];
    float sq = v * v;
    for (int off = 1; off < 64; off <<= 1) sq += __shfl_xor(sq, off, 64);
    __shared__ float p[2];
    if ((d & 63) == 0) p[d >> 6] = sq;
    __syncthreads();
    if (d == 0) w2[k] = p[0] + p[1];
    if (write_wh) {
        _Float16 h = (_Float16)v;                       // RNE
        const int tile = k >> 6, c = k & 63;
        size_t base = (size_t)tile * 8192 + (size_t)(c >> 4) * 2048 + (size_t)(d >> 5) * 512
                    + (size_t)((d >> 3) & 3) * 128 + (size_t)(c & 15) * 8 + (size_t)(d & 7);
        wh[base] = *reinterpret_cast<short*>(&h);
    }
}

// LDS (bytes): lB0 0..32768 | lB1 32768..65536 | lw2 65536..69632 |
//              lx2 69632..70144 | mscr 70144..72192 (128 x 4 ints) |
//              dred 72192..72320
__global__ __launch_bounds__(512, 4)
void dist_argmin_1p(const float* __restrict__ X, const short* __restrict__ wh,
                    const float* __restrict__ w2g, float* __restrict__ cl_out,
                    double* __restrict__ distSlots,
                    int* __restrict__ flag_cnt, int* __restrict__ flag_rows,
                    int flag_cap)
{
    __shared__ __align__(16) char smem[72320];
    char*   lB0  = smem;
    char*   lB1  = smem + 32768;
    float*  lw2  = (float*)(smem + 65536);
    float*  lx2  = (float*)(smem + 69632);
    int*    mscr = (int*)(smem + 70144);
    double* dred = (double*)(smem + 72192);

    const int tid    = threadIdx.x;
    const int lane   = tid & 63;
    const int laneLo = lane & 15;
    const int laneHi = lane >> 4;
    const int wid    = tid >> 6;
    const int rowg   = wid >> 1;
    const int colg   = wid & 1;
    const int rowbase = blockIdx.x * 128;

    // w2 -> LDS (K-loop must have zero global loads so vmcnt counting holds)
    lw2[tid]       = w2g[tid];
    lw2[tid + 512] = w2g[tid + 512];

    // ---- A (fp16 RNE) straight from global into registers + ||x||^2 ----
    f16x8 ah[2][4];
    #pragma unroll
    for (int m = 0; m < 2; ++m) {
        const float* xp = X + (size_t)(rowbase + rowg * 32 + m * 16 + laneLo) * 128 + laneHi * 8;
        float s = 0.f;
        #pragma unroll
        for (int k0b = 0; k0b < 4; ++k0b) {
            float4 v0 = *reinterpret_cast<const float4*>(xp + k0b * 32);
            float4 v1 = *reinterpret_cast<const float4*>(xp + k0b * 32 + 4);
            float fv[8] = {v0.x, v0.y, v0.z, v0.w, v1.x, v1.y, v1.z, v1.w};
            f16x8 hv;
            #pragma unroll
            for (int u = 0; u < 8; ++u) {
                s = fmaf(fv[u], fv[u], s);
                hv[u] = (_Float16)fv[u];               // RNE
            }
            ah[m][k0b] = hv;
        }
        s += __shfl_xor(s, 16, 64);     // combine 4 laneHi dim-slices
        s += __shfl_xor(s, 32, 64);
        if (colg == 0 && laneHi == 0) lx2[rowg * 32 + m * 16 + laneLo] = s;
    }

    // ---- issue phase 0 DMA -> lB0 (32 KB = 128 clusters; 4 x 16B/thread) ----
    #pragma unroll
    for (int q = 0; q < 4; ++q)
        gload_lds16((const char*)wh + wid * 4096 + q * 1024 + lane * 16,
                    lB0 + wid * 4096 + q * 1024);

    // drain my lw2/lx2 ds_writes before the first in-loop barrier
    asm volatile("s_waitcnt lgkmcnt(0)" ::: "memory");
    __builtin_amdgcn_sched_barrier(0);

    float t1v[2][4], t2v[2][4];
    int   t1i[2][4];
    #pragma unroll
    for (int m = 0; m < 2; ++m)
        #pragma unroll
        for (int r = 0; r < 4; ++r) {
            t1v[m][r] = FLT_MAX; t2v[m][r] = FLT_MAX; t1i[m][r] = INT_MAX;
        }

    // one 16KB tile = 64 clusters; ti = global tile index (0..15)
    auto compute = [&](int ti, const char* tileBase) {
        const char* pBb = tileBase + colg * 8192 + lane * 16;
        float w2v[2];
        #pragma unroll
        for (int nt = 0; nt < 2; ++nt)
            w2v[nt] = lw2[ti * 64 + colg * 32 + nt * 16 + laneLo];

        __builtin_amdgcn_s_setprio(1);
        #pragma unroll
        for (int nt = 0; nt < 2; ++nt) {
            f32x4 a0 = (f32x4){0.f, 0.f, 0.f, 0.f};
            f32x4 a1 = (f32x4){0.f, 0.f, 0.f, 0.f};
            #pragma unroll
            for (int k0b = 0; k0b < 4; ++k0b) {
                f16x8 bh = *reinterpret_cast<const f16x8*>(pBb + nt * 4096 + k0b * 1024);
                a0 = __builtin_amdgcn_mfma_f32_16x16x32_f16(ah[0][k0b], bh, a0, 0, 0, 0);
                a1 = __builtin_amdgcn_mfma_f32_16x16x32_f16(ah[1][k0b], bh, a1, 0, 0, 0);
            }
            // dist = w2 - 2*dot_f16; branch-free top-2 values + top-1 index.
            const int col = ti * 64 + colg * 32 + nt * 16 + laneLo;
            #pragma unroll
            for (int r = 0; r < 4; ++r) {
                float dv0 = fmaf(-2.f, a0[r], w2v[nt]);
                t2v[0][r] = fminf(t2v[0][r], fmaxf(t1v[0][r], dv0));
                t1i[0][r] = (dv0 < t1v[0][r]) ? col : t1i[0][r];
                t1v[0][r] = fminf(t1v[0][r], dv0);
                float dv1 = fmaf(-2.f, a1[r], w2v[nt]);
                t2v[1][r] = fminf(t2v[1][r], fmaxf(t1v[1][r], dv1));
                t1i[1][r] = (dv1 < t1v[1][r]) ? col : t1i[1][r];
                t1v[1][r] = fminf(t1v[1][r], dv1);
            }
        }
        __builtin_amdgcn_s_setprio(0);
    };

    const char* cur = lB0;
    char*       nxt = lB1;
    #pragma unroll 1
    for (int p = 0; p < 8; ++p) {
        if (p < 7) {
            const char* src = (const char*)wh + (size_t)(p + 1) * 32768;
            #pragma unroll
            for (int q = 0; q < 4; ++q)
                gload_lds16(src + wid * 4096 + q * 1024 + lane * 16,
                            nxt + wid * 4096 + q * 1024);
            asm volatile("s_waitcnt vmcnt(4)" ::: "memory");  // phase p landed; p+1 in flight
        } else {
            asm volatile("s_waitcnt vmcnt(0)" ::: "memory");
        }
        __builtin_amdgcn_sched_barrier(0);
        __builtin_amdgcn_s_barrier();                         // everyone's phase p landed
        FENCE();
        compute(2 * p,     cur);
        compute(2 * p + 1, cur + 16384);
        if (p < 7) {
            asm volatile("s_waitcnt lgkmcnt(0)" ::: "memory");
            __builtin_amdgcn_sched_barrier(0);
            __builtin_amdgcn_s_barrier();                     // all waves done reading cur
            FENCE();
            char* tmp = nxt; nxt = (char*)cur; cur = tmp;
        }
    }

    // ---- reduce top-2 across the 16 col-lanes (laneLo) of each row ----
    #pragma unroll
    for (int off = 1; off < 16; off <<= 1) {
        #pragma unroll
        for (int m = 0; m < 2; ++m)
            #pragma unroll
            for (int r = 0; r < 4; ++r) {
                float ov1 = __shfl_xor(t1v[m][r], off, 64);
                int   oi1 = __shfl_xor(t1i[m][r], off, 64);
                float ov2 = __shfl_xor(t2v[m][r], off, 64);
                float nt2 = fminf(fminf(t2v[m][r], ov2), fmaxf(t1v[m][r], ov1));
                if (lexlt(ov1, oi1, t1v[m][r], t1i[m][r])) { t1v[m][r] = ov1; t1i[m][r] = oi1; }
                t2v[m][r] = nt2;
            }
    }

    // ---- merge col-halves via LDS ----
    __syncthreads();
    if (colg == 1 && laneLo == 0) {
        #pragma unroll
        for (int m = 0; m < 2; ++m)
            #pragma unroll
            for (int r = 0; r < 4; ++r) {
                const int row = rowg * 32 + m * 16 + laneHi * 4 + r;
                mscr[row * 4 + 0] = __float_as_int(t1v[m][r]);
                mscr[row * 4 + 1] = t1i[m][r];
                mscr[row * 4 + 2] = __float_as_int(t2v[m][r]);
            }
    }
    __syncthreads();
    double local = 0.0;
    if (colg == 0 && laneLo == 0) {
        #pragma unroll
        for (int m = 0; m < 2; ++m)
            #pragma unroll
            for (int r = 0; r < 4; ++r) {
                const int row = rowg * 32 + m * 16 + laneHi * 4 + r;
                float ov1 = __int_as_float(mscr[row * 4 + 0]);
                int   oi1 = mscr[row * 4 + 1];
                float ov2 = __int_as_float(mscr[row * 4 + 2]);
                float b1v = t1v[m][r], b2v;
                int   b1i = t1i[m][r];
                b2v = fminf(fminf(t2v[m][r], ov2), fmaxf(b1v, ov1));
                if (lexlt(ov1, oi1, b1v, b1i)) { b1v = ov1; b1i = oi1; }
                const int grow = rowbase + row;
                if (b2v - b1v < TAU) {                 // near-tie: exact rescan
                    int slot = atomicAdd(flag_cnt, 1);
                    if (slot < flag_cap) {
                        flag_rows[slot] = grow;
                    } else {
                        cl_out[grow] = (float)b1i;
                        local += (double)(b1v + lx2[row]);
                    }
                } else {
                    cl_out[grow] = (float)b1i;
                    local += (double)(b1v + lx2[row]);
                }
            }
        dred[rowg * 4 + laneHi] = local;
    }
    __syncthreads();
    if (tid == 0) {
        double tt = 0.0;
        for (int i = 0; i < 16; ++i) tt += dred[i];
        distSlots[blockIdx.x] = tt;          // NO atomic: per-block slot
    }
}

// refine3: one BLOCK per flagged row (grid-stride). W staged chunk-wise into
// padded LDS [128][129] (conflict-free), 256 threads compute f32 dists from
// LDS, block top-2 (lexicographic), wave-parallel exact f64 pair decision.
// Inertia goes to refSlots[blockIdx] — no atomics.
__global__ __launch_bounds__(256)
void refine3_kernel(const float* __restrict__ X, const float* __restrict__ W,
                    const float* __restrict__ w2,
                    const int* __restrict__ flag_cnt,
                    const int* __restrict__ flag_rows, int flag_cap,
                    float* __restrict__ cl_out, double* __restrict__ refSlots)
{
    __shared__ __align__(16) float wt[128 * 129];   // 66048 B, +1 pad
    __shared__ float xrow[128];
    __shared__ float pd[256];
    __shared__ float cv1[128], cv2[128];
    __shared__ int   ci1[128], ci2[128];
    __shared__ int   gi[2];

    int n = *flag_cnt;
    if (n > flag_cap) n = flag_cap;
    const int tid = threadIdx.x;
    double acc = 0.0;

    for (int f = blockIdx.x; f < n; f += gridDim.x) {
        const int row = flag_rows[f];
        if (tid < 128) xrow[tid] = X[(size_t)row * 128 + tid];

        float tv1 = FLT_MAX, tv2 = FLT_MAX;
        int   ti1 = INT_MAX, ti2 = INT_MAX;
        #pragma unroll 1
        for (int ch = 0; ch < 8; ++ch) {
            __syncthreads();               // xrow ready / prev readers done
            // stage 128x128 f32 W chunk -> wt[c][129] (coalesced reads)
            #pragma unroll
            for (int r = 0; r < 16; ++r) {
                const int idx = (r * 256 + tid) * 4;
                float4 v = *reinterpret_cast<const float4*>(W + (size_t)ch * 16384 + idx);
                const int c = idx >> 7, d = idx & 127;
                float* w = wt + c * 129 + d;
                w[0] = v.x; w[1] = v.y; w[2] = v.z; w[3] = v.w;
            }
            __syncthreads();
            // partial 64-dim dots: thread (c=tid&127, h=tid>>7)
            {
                const int c = tid & 127, h = tid >> 7;
                const float* wp = wt + c * 129 + h * 64;
                const float* xp = xrow + h * 64;
                float s = 0.f;
                #pragma unroll 16
                for (int d = 0; d < 64; ++d) s = fmaf(xp[d], wp[d], s);
                pd[tid] = s;
            }
            __syncthreads();
            if (tid < 128) {
                const float dot = pd[tid] + pd[tid + 128];
                const int cc = ch * 128 + tid;
                const float dv = fmaf(-2.f, dot, w2[cc]);
                if (lexlt(dv, cc, tv1, ti1)) { tv2 = tv1; ti2 = ti1; tv1 = dv; ti1 = cc; }
                else if (lexlt(dv, cc, tv2, ti2)) { tv2 = dv; ti2 = cc; }
            }
        }
        __syncthreads();
        if (tid < 128) { cv1[tid] = tv1; ci1[tid] = ti1; cv2[tid] = tv2; ci2[tid] = ti2; }
        __syncthreads();
        if (tid == 0) {
            float b1 = FLT_MAX, b2 = FLT_MAX; int j1 = INT_MAX, j2 = INT_MAX;
            for (int t = 0; t < 128; ++t) {
                const float a1 = cv1[t]; const int a1i = ci1[t];
                if (lexlt(a1, a1i, b1, j1)) {
                    if (lexlt(b1, j1, cv2[t], ci2[t])) { b2 = b1; j2 = j1; }
                    else                               { b2 = cv2[t]; j2 = ci2[t]; }
                    b1 = a1; j1 = a1i;
                } else if (lexlt(a1, a1i, b2, j2)) { b2 = a1; j2 = a1i; }
            }
            gi[0] = j1; gi[1] = j2;
        }
        __syncthreads();
        if (tid < 64) {
            const int i1 = gi[0], i2 = gi[1];
            const float* wa = W + (size_t)i1 * 128;
            const float* wb = W + (size_t)i2 * 128;
            double d1 = 0.0, d2 = 0.0;
            #pragma unroll
            for (int j = 0; j < 2; ++j) {
                const int d = tid * 2 + j;
                const double xv = (double)xrow[d];
                const double e1 = xv - (double)wa[d]; d1 = fma(e1, e1, d1);
                const double e2 = xv - (double)wb[d]; d2 = fma(e2, e2, d2);
            }
            #pragma unroll
            for (int off = 1; off < 64; off <<= 1) {
                d1 += __shfl_xor(d1, off, 64);
                d2 += __shfl_xor(d2, off, 64);
            }
            if (tid == 0) {
                int win; double dw;
                if (d1 < d2 || (d1 == d2 && i1 < i2)) { win = i1; dw = d1; }
                else                                  { win = i2; dw = d2; }
                cl_out[row] = (float)win;
                acc += dw;
            }
        }
        __syncthreads();                   // pair readers done before next xrow
    }
    if (tid == 0) refSlots[blockIdx.x] = acc;   // slot (memset-zeroed)
}

// ---------------- fallback (3-pass bf16 in-kernel conversion, ws too small) --
__global__ __launch_bounds__(512, 1)
void dist_argmin_v2(const float* __restrict__ X, const float* __restrict__ W,
                    const float* __restrict__ w2g, float* __restrict__ cl_out,
                    double* __restrict__ inertia_acc,
                    int* __restrict__ flag_cnt, int* __restrict__ flag_rows,
                    int flag_cap)
{
    __shared__ __align__(16) char smem[133760];
    short*  Areg = (short*)smem;
    short*  Breg = (short*)(smem + 65536);
    int*    mscr = (int*)(smem + 131072);
    float*  lx2  = (float*)(smem + 131072 + 2048);
    double* dred = (double*)(smem + 131072 + 2048 + 512);

    const int tid    = threadIdx.x;
    const int lane   = tid & 63;
    const int laneLo = lane & 15;
    const int laneHi = lane >> 4;
    const int wid    = tid >> 6;
    const int rowg   = wid >> 1;
    const int colg   = wid & 1;
    const int rowbase = blockIdx.x * 128;

    {
        const int r = tid >> 2, q = tid & 3;
        float s = 0.f;
        #pragma unroll
        for (int j = 0; j < 8; ++j) {
            const int d0 = q * 4 + j * 16;
            float4 v = *reinterpret_cast<const float4*>(X + (size_t)(rowbase + r) * 128 + d0);
            float fv[4] = {v.x, v.y, v.z, v.w};
            s16x4 hv, lv;
            #pragma unroll
            for (int u = 0; u < 4; ++u) {
                s = fmaf(fv[u], fv[u], s);
                short h = f2bf_trunc(fv[u]);
                short l = f2bf_trunc(fv[u] - bf2f(h));
                hv[u] = h; lv[u] = l;
            }
            const int kb = d0 >> 3, off = d0 & 7;
            short* pa = Areg + (kb * 128 + r) * 8 + off;
            *reinterpret_cast<s16x4*>(pa)         = hv;
            *reinterpret_cast<s16x4*>(pa + 16384) = lv;
        }
        s += __shfl_xor(s, 1, 64);
        s += __shfl_xor(s, 2, 64);
        if (q == 0) lx2[r] = s;
    }

    float t1v[2][4], t2v[2][4];
    int   t1i[2][4];
    #pragma unroll
    for (int m = 0; m < 2; ++m)
        #pragma unroll
        for (int r = 0; r < 4; ++r) {
            t1v[m][r] = FLT_MAX; t2v[m][r] = FLT_MAX; t1i[m][r] = INT_MAX;
        }

    const char* pAbase = smem + laneHi * 2048 + (rowg * 32 + laneLo) * 16;
    const char* pBbase = smem + 65536 + colg * 16384 + lane * 16;

    for (int iter = 0; iter < 8; ++iter) {
        __syncthreads();
        {
            const int c = tid >> 2, q = tid & 3;
            const int nt = c >> 4, c15 = c & 15;
            #pragma unroll
            for (int j = 0; j < 8; ++j) {
                const int d0 = q * 4 + j * 16;
                float4 v = *reinterpret_cast<const float4*>(W + (size_t)(iter * 128 + c) * 128 + d0);
                float fv[4] = {v.x, v.y, v.z, v.w};
                s16x4 hv, lv;
                #pragma unroll
                for (int u = 0; u < 4; ++u) {
                    short h = f2bf_trunc(fv[u]);
                    short l = f2bf_trunc(fv[u] - bf2f(h));
                    hv[u] = h; lv[u] = l;
                }
                const int k0b = d0 >> 5, sub = (d0 >> 3) & 3, jj = d0 & 7;
                short* pb = Breg + ((nt * 4 + k0b) * 64 + sub * 16 + c15) * 8 + jj;
                *reinterpret_cast<s16x4*>(pb)         = hv;
                *reinterpret_cast<s16x4*>(pb + 16384) = lv;
            }
        }
        float w2v[4];
        #pragma unroll
        for (int nt = 0; nt < 4; ++nt)
            w2v[nt] = w2g[iter * 128 + colg * 64 + nt * 16 + laneLo];
        __syncthreads();

        f32x4 acc[2][4];
        #pragma unroll
        for (int m = 0; m < 2; ++m)
            #pragma unroll
            for (int nt = 0; nt < 4; ++nt)
                acc[m][nt] = (f32x4){0.f, 0.f, 0.f, 0.f};

        #pragma unroll
        for (int k0b = 0; k0b < 4; ++k0b) {
            bf16x8 ah[2], al[2];
            #pragma unroll
            for (int m = 0; m < 2; ++m) {
                ah[m] = *reinterpret_cast<const bf16x8*>(pAbase + k0b * 8192 + m * 256);
                al[m] = *reinterpret_cast<const bf16x8*>(pAbase + 32768 + k0b * 8192 + m * 256);
            }
            #pragma unroll
            for (int nt = 0; nt < 4; ++nt) {
                bf16x8 bh = *reinterpret_cast<const bf16x8*>(pBbase + nt * 4096 + k0b * 1024);
                bf16x8 bl = *reinterpret_cast<const bf16x8*>(pBbase + 32768 + nt * 4096 + k0b * 1024);
                #pragma unroll
                for (int m = 0; m < 2; ++m) {
                    acc[m][nt] = __builtin_amdgcn_mfma_f32_16x16x32_bf16(ah[m], bh, acc[m][nt], 0, 0, 0);
                    acc[m][nt] = __builtin_amdgcn_mfma_f32_16x16x32_bf16(ah[m], bl, acc[m][nt], 0, 0, 0);
                    acc[m][nt] = __builtin_amdgcn_mfma_f32_16x16x32_bf16(al[m], bh, acc[m][nt], 0, 0, 0);
                }
            }
        }

        #pragma unroll
        for (int nt = 0; nt < 4; ++nt) {
            const int col = iter * 128 + colg * 64 + nt * 16 + laneLo;
            #pragma unroll
            for (int m = 0; m < 2; ++m)
                #pragma unroll
                for (int r = 0; r < 4; ++r) {
                    float dv = fmaf(-2.f, acc[m][nt][r], w2v[nt]);
                    float hi = fmaxf(t1v[m][r], dv);
                    t2v[m][r] = fminf(t2v[m][r], hi);
                    bool cnd = dv < t1v[m][r];
                    t1i[m][r] = cnd ? col : t1i[m][r];
                    t1v[m][r] = fminf(t1v[m][r], dv);
                }
        }
    }

    #pragma unroll
    for (int off = 1; off < 16; off <<= 1) {
        #pragma unroll
        for (int m = 0; m < 2; ++m)
            #pragma unroll
            for (int r = 0; r < 4; ++r) {
                float ov1 = __shfl_xor(t1v[m][r], off, 64);
                int   oi1 = __shfl_xor(t1i[m][r], off, 64);
                float ov2 = __shfl_xor(t2v[m][r], off, 64);
                float nt2 = fminf(fminf(t2v[m][r], ov2), fmaxf(t1v[m][r], ov1));
                if (lexlt(ov1, oi1, t1v[m][r], t1i[m][r])) { t1v[m][r] = ov1; t1i[m][r] = oi1; }
                t2v[m][r] = nt2;
            }
    }

    __syncthreads();
    if (colg == 1 && laneLo == 0) {
        #pragma unroll
        for (int m = 0; m < 2; ++m)
            #pragma unroll
            for (int r = 0; r < 4; ++r) {
                const int row = rowg * 32 + m * 16 + laneHi * 4 + r;
                mscr[row * 4 + 0] = __float_as_int(t1v[m][r]);
                mscr[row * 4 + 1] = t1i[m][r];
                mscr[row * 4 + 2] = __float_as_int(t2v[m][r]);
            }
    }
    __syncthreads();
    double local = 0.0;
    if (colg == 0 && laneLo == 0) {
        #pragma unroll
        for (int m = 0; m < 2; ++m)
            #pragma unroll
            for (int r = 0; r < 4; ++r) {
                const int row = rowg * 32 + m * 16 + laneHi * 4 + r;
                float ov1 = __int_as_float(mscr[row * 4 + 0]);
                int   oi1 = mscr[row * 4 + 1];
                float ov2 = __int_as_float(mscr[row * 4 + 2]);
                float b1v = t1v[m][r], b2v;
                int   b1i = t1i[m][r];
                b2v = fminf(fminf(t2v[m][r], ov2), fmaxf(b1v, ov1));
                if (lexlt(ov1, oi1, b1v, b1i)) { b1v = ov1; b1i = oi1; }
                const int grow = rowbase + row;
                if (b2v - b1v < 1e-3f) {
                    int slot = atomicAdd(flag_cnt, 1);
                    if (slot < flag_cap) flag_rows[slot] = grow;
                    else { cl_out[grow] = (float)b1i; local += (double)(b1v + lx2[row]); }
                } else {
                    cl_out[grow] = (float)b1i;
                    local += (double)(b1v + lx2[row]);
                }
            }
        dred[rowg * 4 + laneHi] = local;
    }
    __syncthreads();
    if (tid == 0) {
        double t = 0.0;
        for (int i = 0; i < 16; ++i) t += dred[i];
        atomicAdd(inertia_acc, t);           // fallback path only
    }
}

__global__ void finalize_kernel(const float* __restrict__ W, const float* __restrict__ w2,
                                const double* __restrict__ acc0,
                                const double* __restrict__ distSlots,
                                const double* __restrict__ refSlots,
                                float* __restrict__ out)
{
    __shared__ float  sh1[128], sh2[128];
    __shared__ double dsum[128];
    int d = threadIdx.x;                       // 128 threads
    float s = 0.f;
    for (int k = 0; k < 1024; ++k) s += W[(size_t)k * 128 + d];
    float t = 0.f;
    for (int j = 0; j < 8; ++j) t += w2[d + 128 * j];
    double dt = 0.0;
    for (int j = 0; j < 8; ++j) dt += distSlots[d + 128 * j];
    for (int j = 0; j < 4; ++j) dt += refSlots[d + 128 * j];
    sh1[d] = s * s;
    sh2[d] = t;
    dsum[d] = dt;
    __syncthreads();
    for (int off = 64; off > 0; off >>= 1) {
        if (d < off) {
            sh1[d] += sh1[d + off];
            sh2[d] += sh2[d + off];
            dsum[d] += dsum[d + off];
        }
        __syncthreads();
    }
    if (d == 0) {
        float xe = 2.f * sh2[0] - sh1[0];      // 2*trace(G) - sum(G)
        out[1] = xe / 1024.f;
        out[0] = (float)((*acc0 + dsum[0]) / 131072.0);
    }
}

extern "C" void kernel_launch(void* const* d_in, const int* in_sizes, int n_in,
                              void* d_out, int out_size, void* d_ws, size_t ws_size,
                              hipStream_t stream)
{
    const float* X = (const float*)d_in[0];          // [131072,128] f32
    const float* W = (const float*)d_in[1];          // [1024,128]   f32
    float* out = (float*)d_out;                       // [131074]     f32
    char* ws = (char*)d_ws;

    double* acc0      = (double*)ws;
    int*    flag_cnt  = (int*)(ws + 8);
    float*  w2        = (float*)(ws + 16);
    double* distSlots = (double*)(ws + 4608);
    double* refSlots  = (double*)(ws + 12800);
    short*  wh        = (short*)(ws + 16896);
    int*    flags     = (int*)(ws + 541184);
    const int FCAP = 16384;
    const size_t NEED = 606720;

    const bool precomp = ws_size >= NEED;

    hipMemsetAsync(ws, 0, 16896, stream);    // acc0 + flag_cnt + w2 + slots

    if (precomp) {
        wprep_kernel<<<1024, 128, 0, stream>>>(W, w2, wh, 1);
        dist_argmin_1p<<<1024, 512, 0, stream>>>(X, wh, w2, out + 2, distSlots,
                                                 flag_cnt, flags, FCAP);
        refine3_kernel<<<512, 256, 0, stream>>>(X, W, w2, flag_cnt, flags, FCAP,
                                                out + 2, refSlots);
    } else {
        int* flagsf = (int*)(ws + 16896);
        long cap = ((long)ws_size - 16896) / 4;
        int capf = cap < 0 ? 0 : (cap > 131072 ? 131072 : (int)cap);
        wprep_kernel<<<1024, 128, 0, stream>>>(W, w2, (short*)flagsf, 0);
        dist_argmin_v2<<<1024, 512, 0, stream>>>(X, W, w2, out + 2, acc0,
                                                 flag_cnt, flagsf, capf);
        refine3_kernel<<<512, 256, 0, stream>>>(X, W, w2, flag_cnt, flagsf, capf,
                                                out + 2, refSlots);
    }
    finalize_kernel<<<1, 128, 0, stream>>>(W, w2, acc0, distSlots, refSlots, out);
}